// Round 6
// baseline (77.057 us; speedup 1.0000x reference)
//
#include <hip/hip_runtime.h>
#include <math.h>
#include <float.h>

#define BATCH 1024
#define DIM 128
#define EPSV 1e-12f
#define MARGIN 0.5f
#define INTRA_MARGIN 0.1f
#define LAMDA 0.5f
#define NRG 128          // row-groups of 16 rows (2048 / 16)

typedef __attribute__((ext_vector_type(8))) short s16x8;   // 8 bf16 (4 VGPRs)
typedef __attribute__((ext_vector_type(4))) float f32x4;   // MFMA C/D

__device__ __forceinline__ ushort f2bf(float f) {          // RNE fp32 -> bf16
    unsigned u = __float_as_uint(f);
    return (ushort)((u + 0x7fffu + ((u >> 16) & 1u)) >> 16);
}

// ---------------- Kernel A: feat -> bf16 + fp32 row norms + counter resets ----------------
// 256 blocks x 128 threads (all CUs); 16 threads per row, 8 floats per thread.
__global__ __launch_bounds__(128) void prep_kernel(
    const float* __restrict__ feat, ushort* __restrict__ bhi,
    float* __restrict__ norm2, unsigned int* __restrict__ counters)
{
    const int t = threadIdx.x;
    if (blockIdx.x == 0) {                 // counters[0..127]=rg, [128]=global
        counters[t] = 0u;
        if (t == 0) counters[NRG] = 0u;
    }

    const int gt  = blockIdx.x * 128 + t;  // 0..32767
    const int row = gt >> 4, seg = gt & 15;
    const float4* p = reinterpret_cast<const float4*>(feat + (size_t)row * DIM + seg * 8);
    const float4 a = p[0], b = p[1];
    const float v[8] = {a.x, a.y, a.z, a.w, b.x, b.y, b.z, b.w};
    ushort h[8];
    float n = 0.0f;
    #pragma unroll
    for (int e = 0; e < 8; ++e) {
        h[e] = f2bf(v[e]);
        n = fmaf(v[e], v[e], n);
    }
    uint4 uh;
    uh.x = (uint)h[0] | ((uint)h[1] << 16); uh.y = (uint)h[2] | ((uint)h[3] << 16);
    uh.z = (uint)h[4] | ((uint)h[5] << 16); uh.w = (uint)h[6] | ((uint)h[7] << 16);
    *reinterpret_cast<uint4*>(bhi + (size_t)row * DIM + seg * 8) = uh;
    n += __shfl_xor(n, 1); n += __shfl_xor(n, 2);
    n += __shfl_xor(n, 4); n += __shfl_xor(n, 8);
    if ((t & 15) == 0) norm2[row] = n;
}

// ---------------- Kernel B: MFMA gram + selection; pair-merge + final sum ----------------
// 256 blocks x 512 threads. Block = (rowgroup rg, col-half ch): 16 rows x 512 cols.
// Wave w (0..7) covers cols [ch*512 + w*64, +64) as 4 subtiles of 16.
__global__ __launch_bounds__(512) void gemm_finalize_kernel(
    const ushort* __restrict__ bhi, const float* __restrict__ norm2,
    const float* __restrict__ feat,
    const int* __restrict__ label1, const int* __restrict__ label2,
    float4* __restrict__ cand, float* __restrict__ partial,
    unsigned int* __restrict__ counters, float* __restrict__ out)
{
    const int bid   = blockIdx.x;
    const int rg    = bid >> 1;            // 0..127
    const int ch    = bid & 1;             // col half
    const int half  = rg >> 6;             // 64 rowgroups per half
    const int arow0 = (rg & 63) * 16;      // row base within half
    const int aglob0 = half * BATCH + arow0;
    const int bglob0 = (half ^ 1) * BATCH;

    const int t = threadIdx.x;
    const int w = t >> 6, lane = t & 63;
    const int l15 = lane & 15, kg = lane >> 4;

    const int* labA = half ? label2 : label1;
    const int* labB = half ? label1 : label2;

    // ---- operands: 4 subtiles of 16 cols ----
    const size_t abase = (size_t)(aglob0 + l15) * DIM;
    int jcol[4]; float nb[4]; int lb[4]; size_t bbase[4];
    #pragma unroll
    for (int s = 0; s < 4; ++s) {
        jcol[s]  = ch * 512 + w * 64 + s * 16 + l15;
        const int bg = bglob0 + jcol[s];
        bbase[s] = (size_t)bg * DIM;
        nb[s] = norm2[bg];
        lb[s] = labB[jcol[s]];
    }

    f32x4 acc[4];
    #pragma unroll
    for (int s = 0; s < 4; ++s) acc[s] = (f32x4){0.f, 0.f, 0.f, 0.f};

    #pragma unroll
    for (int kt = 0; kt < 4; ++kt) {
        const int koff = kt * 32 + kg * 8;
        const s16x8 ah = *reinterpret_cast<const s16x8*>(bhi + abase + koff);
        #pragma unroll
        for (int s = 0; s < 4; ++s) {
            const s16x8 bh = *reinterpret_cast<const s16x8*>(bhi + bbase[s] + koff);
            acc[s] = __builtin_amdgcn_mfma_f32_16x16x32_bf16(ah, bh, acc[s], 0, 0, 0);
        }
    }

    // ---- selection in d^2 domain; C/D layout: col=l15, row=kg*4+reg ----
    float na[4]; int la[4];
    #pragma unroll
    for (int r = 0; r < 4; ++r) {
        na[r] = norm2[aglob0 + kg * 4 + r];
        la[r] = labA[arow0 + kg * 4 + r];
    }

    float bpv[4], bnv[4]; int bpj[4], bnj[4];
    #pragma unroll
    for (int r = 0; r < 4; ++r) { bpv[r] = -1.0f; bpj[r] = 0x7fffffff; bnv[r] = FLT_MAX; bnj[r] = 0x7fffffff; }

    #pragma unroll
    for (int s = 0; s < 4; ++s) {
        #pragma unroll
        for (int r = 0; r < 4; ++r) {
            const float d2 = fmaxf(na[r] + nb[s] - 2.0f * acc[s][r], 0.0f);
            const bool same = (la[r] == lb[s]);
            const float pv = same ? d2 : 0.0f;
            const float nv = same ? FLT_MAX : d2;
            // jcol ascending in s -> strict compares keep first occurrence
            if (pv > bpv[r]) { bpv[r] = pv; bpj[r] = jcol[s]; }
            if (nv < bnv[r]) { bnv[r] = nv; bnj[r] = jcol[s]; }
        }
    }

    // reduce across the 16 lanes of each row group (masks < 16 keep kg fixed)
    #pragma unroll
    for (int r = 0; r < 4; ++r) {
        #pragma unroll
        for (int m = 8; m > 0; m >>= 1) {
            const float opv = __shfl_xor(bpv[r], m); const int opj = __shfl_xor(bpj[r], m);
            if (opv > bpv[r] || (opv == bpv[r] && opj < bpj[r])) { bpv[r] = opv; bpj[r] = opj; }
            const float onv = __shfl_xor(bnv[r], m); const int onj = __shfl_xor(bnj[r], m);
            if (onv < bnv[r] || (onv == bnv[r] && onj < bnj[r])) { bnv[r] = onv; bnj[r] = onj; }
        }
    }

    // ---- cross-wave combine: 16 rows x 8 col-chunks ----
    __shared__ float L_pv[16][8]; __shared__ int L_pj[16][8];
    __shared__ float L_nv[16][8]; __shared__ int L_nj[16][8];
    if (l15 == 0) {
        #pragma unroll
        for (int r = 0; r < 4; ++r) {
            const int rib = kg * 4 + r;
            L_pv[rib][w] = bpv[r]; L_pj[rib][w] = bpj[r];
            L_nv[rib][w] = bnv[r]; L_nj[rib][w] = bnj[r];
        }
    }
    __syncthreads();

    if (t < 16) {
        float pv = -1.0f; int pj = 0x7fffffff; float nv = FLT_MAX; int nj = 0x7fffffff;
        #pragma unroll
        for (int c = 0; c < 8; ++c) {   // ascending col ranges -> tie keeps first
            const float v1 = L_pv[t][c]; const int j1 = L_pj[t][c];
            if (v1 > pv || (v1 == pv && j1 < pj)) { pv = v1; pj = j1; }
            const float v2 = L_nv[t][c]; const int j2 = L_nj[t][c];
            if (v2 < nv || (v2 == nv && j2 < nj)) { nv = v2; nj = j2; }
        }
        cand[rg * 32 + ch * 16 + t] =
            make_float4(pv, __int_as_float(pj), nv, __int_as_float(nj));
    }
    __syncthreads();
    __threadfence();                       // release cand writes

    __shared__ int s_old;
    if (t == 0) s_old = (int)atomicAdd(&counters[rg], 1u);
    __syncthreads();

    if (s_old == 1) {                      // second block of the pair: merge + finish rg
        __threadfence();                   // acquire other block's cand
        __shared__ int s_pp[16], s_pn[16];
        __shared__ float s_fp[16], s_cn[16];
        if (t < 16) {
            const float4 c0 = cand[rg * 32 + t];        // cols 0..511 (lower indices)
            const float4 c1 = cand[rg * 32 + 16 + t];   // cols 512..1023
            float pv = c0.x; int pj = __float_as_int(c0.y);
            if (c1.x > pv) { pv = c1.x; pj = __float_as_int(c1.y); }  // tie -> keep c0 (lower j)
            float nv = c0.z; int nj = __float_as_int(c0.w);
            if (c1.z < nv) { nv = c1.z; nj = __float_as_int(c1.w); }
            s_pp[t] = pj > (BATCH - 1) ? (BATCH - 1) : pj;
            s_pn[t] = nj > (BATCH - 1) ? (BATCH - 1) : nj;
            s_fp[t] = (pv > 0.0f) ? sqrtf(pv + EPSV) : 0.0f;   // no-positive row -> 0
            s_cn[t] = sqrtf(nv + EPSV);
        }
        __syncthreads();

        // ---- intra distances (exact fp32): 16 rows x 16 lanes ----
        __shared__ float ls[16];
        if (t < 256) {
            const int g = t >> 4, sl = t & 15;
            const float* fB = feat + (size_t)(half ^ 1) * BATCH * DIM;  // f_intra
            const float4* x = reinterpret_cast<const float4*>(fB + (size_t)s_pp[g] * DIM + sl * 8);
            const float4* y = reinterpret_cast<const float4*>(fB + (size_t)s_pn[g] * DIM + sl * 8);
            const float4 x0 = x[0], x1 = x[1], y0 = y[0], y1 = y[1];
            float d, d2;
            d = x0.x - y0.x; d2  = d * d;  d = x0.y - y0.y; d2 += d * d;
            d = x0.z - y0.z; d2 += d * d;  d = x0.w - y0.w; d2 += d * d;
            d = x1.x - y1.x; d2 += d * d;  d = x1.y - y1.y; d2 += d * d;
            d = x1.z - y1.z; d2 += d * d;  d = x1.w - y1.w; d2 += d * d;
            d2 += __shfl_xor(d2, 1); d2 += __shfl_xor(d2, 2);
            d2 += __shfl_xor(d2, 4); d2 += __shfl_xor(d2, 8);
            if (sl == 0) {
                const float gd = sqrtf(d2 + EPSV);
                const float loss = fmaxf(s_fp[g] - s_cn[g] + MARGIN, 0.0f)
                                 + LAMDA * fmaxf(INTRA_MARGIN - gd, 0.0f);
                ls[g] = loss * (1.0f / (float)BATCH);
            }
        }
        __syncthreads();

        if (t == 0) {
            float s = 0.0f;
            #pragma unroll
            for (int i = 0; i < 16; ++i) s += ls[i];
            partial[rg] = s;
            __threadfence();
            const unsigned int old = atomicAdd(&counters[NRG], 1u);
            if (old == (NRG - 1)) {        // last rowgroup finished
                __threadfence();
                float tot = 0.0f;
                for (int i = 0; i < NRG; ++i) tot += partial[i];  // fixed order -> deterministic
                out[0] = tot;
            }
        }
    }
}

extern "C" void kernel_launch(void* const* d_in, const int* in_sizes, int n_in,
                              void* d_out, int out_size, void* d_ws, size_t ws_size,
                              hipStream_t stream) {
    const float* feat   = (const float*)d_in[0];
    const int*   label1 = (const int*)d_in[1];
    const int*   label2 = (const int*)d_in[2];
    float* out = (float*)d_out;

    char* ws = (char*)d_ws;
    float*        partial  = (float*)(ws);                 // 512 B
    unsigned int* counters = (unsigned int*)(ws + 1024);   // 129 u32
    float4*       cand     = (float4*)(ws + 4096);         // 128*32*16 B = 64 KB
    ushort*       bhi      = (ushort*)(ws + 128 * 1024);   // 512 KB
    float*        norm2    = (float*)(ws + 704 * 1024);    // 8 KB

    prep_kernel<<<dim3(256), dim3(128), 0, stream>>>(feat, bhi, norm2, counters);
    gemm_finalize_kernel<<<dim3(256), dim3(512), 0, stream>>>(
        bhi, norm2, feat, label1, label2, cand, partial, counters, out);
}

// Round 7
// 32.735 us; speedup vs baseline: 2.3539x; 2.3539x over previous
//
#include <hip/hip_runtime.h>
#include <math.h>
#include <float.h>

#define BATCH 1024
#define DIM 128
#define EPSV 1e-12f
#define MARGIN 0.5f
#define INTRA_MARGIN 0.1f
#define LAMDA 0.5f
#define NRG 256          // row-groups of 8 rows (2048 / 8)

typedef __attribute__((ext_vector_type(8))) short s16x8;   // 8 bf16 (4 VGPRs)
typedef __attribute__((ext_vector_type(4))) float f32x4;   // MFMA C/D

__device__ __forceinline__ ushort f2bf(float f) {          // RNE fp32 -> bf16
    unsigned u = __float_as_uint(f);
    return (ushort)((u + 0x7fffu + ((u >> 16) & 1u)) >> 16);
}

// ---------------- Kernel A: feat -> bf16 + fp32 row norms + counter reset ----------------
// 256 blocks x 128 threads (all CUs); 16 threads per row, 8 floats per thread.
__global__ __launch_bounds__(128) void prep_kernel(
    const float* __restrict__ feat, ushort* __restrict__ bhi,
    float* __restrict__ norm2, unsigned int* __restrict__ counter)
{
    const int t = threadIdx.x;
    if (blockIdx.x == 0 && t == 0) counter[0] = 0u;

    const int gt  = blockIdx.x * 128 + t;  // 0..32767
    const int row = gt >> 4, seg = gt & 15;
    const float4* p = reinterpret_cast<const float4*>(feat + (size_t)row * DIM + seg * 8);
    const float4 a = p[0], b = p[1];
    const float v[8] = {a.x, a.y, a.z, a.w, b.x, b.y, b.z, b.w};
    ushort h[8];
    float n = 0.0f;
    #pragma unroll
    for (int e = 0; e < 8; ++e) {
        h[e] = f2bf(v[e]);
        n = fmaf(v[e], v[e], n);
    }
    uint4 uh;
    uh.x = (uint)h[0] | ((uint)h[1] << 16); uh.y = (uint)h[2] | ((uint)h[3] << 16);
    uh.z = (uint)h[4] | ((uint)h[5] << 16); uh.w = (uint)h[6] | ((uint)h[7] << 16);
    *reinterpret_cast<uint4*>(bhi + (size_t)row * DIM + seg * 8) = uh;
    n += __shfl_xor(n, 1); n += __shfl_xor(n, 2);
    n += __shfl_xor(n, 4); n += __shfl_xor(n, 8);
    if ((t & 15) == 0) norm2[row] = n;
}

// ---------------- Kernel B: MFMA gram + selection + intra + final sum ----------------
// 256 blocks x 512 threads (all CUs). Block = 8 rows (one half) x ALL 1024 cols.
// Wave w covers cols [w*128, w*128+128) as 8 subtiles of 16.
// MFMA A-fragment duplicates rows (l15&7); C rows 8..15 are ignored at merge.
__global__ __launch_bounds__(512) void gemm_finalize_kernel(
    const ushort* __restrict__ bhi, const float* __restrict__ norm2,
    const float* __restrict__ feat,
    const int* __restrict__ label1, const int* __restrict__ label2,
    float* __restrict__ partial, unsigned int* __restrict__ counter,
    float* __restrict__ out)
{
    const int rg    = blockIdx.x;            // 0..255
    const int half  = rg >> 7;               // 128 rowgroups per half
    const int arow0 = (rg & 127) * 8;        // row base within half
    const int aglob0 = half * BATCH + arow0; // row base in 2048-row arrays
    const int bglob0 = (half ^ 1) * BATCH;

    const int t = threadIdx.x;
    const int w = t >> 6, lane = t & 63;
    const int l15 = lane & 15, kg = lane >> 4;

    const int* labA = half ? label2 : label1;
    const int* labB = half ? label1 : label2;

    // ---- operands: 8 subtiles of 16 cols; A rows duplicated via l15&7 ----
    const size_t abase = (size_t)(aglob0 + (l15 & 7)) * DIM;
    int jcol[8]; float nb[8]; int lb[8]; size_t bbase[8];
    #pragma unroll
    for (int s = 0; s < 8; ++s) {
        jcol[s]  = w * 128 + s * 16 + l15;
        const int bg = bglob0 + jcol[s];
        bbase[s] = (size_t)bg * DIM;
        nb[s] = norm2[bg];
        lb[s] = labB[jcol[s]];
    }

    f32x4 acc[8];
    #pragma unroll
    for (int s = 0; s < 8; ++s) acc[s] = (f32x4){0.f, 0.f, 0.f, 0.f};

    #pragma unroll
    for (int kt = 0; kt < 4; ++kt) {
        const int koff = kt * 32 + kg * 8;
        const s16x8 ah = *reinterpret_cast<const s16x8*>(bhi + abase + koff);
        #pragma unroll
        for (int s = 0; s < 8; ++s) {
            const s16x8 bh = *reinterpret_cast<const s16x8*>(bhi + bbase[s] + koff);
            acc[s] = __builtin_amdgcn_mfma_f32_16x16x32_bf16(ah, bh, acc[s], 0, 0, 0);
        }
    }

    // ---- selection in d^2 domain; C/D layout: col=l15, row=kg*4+reg ----
    // rows with rib=kg*4+r >= 8 are duplicates of rib-8 and are ignored at merge
    float na[4]; int la[4];
    #pragma unroll
    for (int r = 0; r < 4; ++r) {
        const int rr = (kg * 4 + r) & 7;
        na[r] = norm2[aglob0 + rr];
        la[r] = labA[arow0 + rr];
    }

    float bpv[4], bnv[4]; int bpj[4], bnj[4];
    #pragma unroll
    for (int r = 0; r < 4; ++r) { bpv[r] = -1.0f; bpj[r] = 0x7fffffff; bnv[r] = FLT_MAX; bnj[r] = 0x7fffffff; }

    #pragma unroll
    for (int s = 0; s < 8; ++s) {
        #pragma unroll
        for (int r = 0; r < 4; ++r) {
            const float d2 = fmaxf(na[r] + nb[s] - 2.0f * acc[s][r], 0.0f);
            const bool same = (la[r] == lb[s]);
            const float pv = same ? d2 : 0.0f;
            const float nv = same ? FLT_MAX : d2;
            // jcol ascending in s -> strict compares keep first occurrence
            if (pv > bpv[r]) { bpv[r] = pv; bpj[r] = jcol[s]; }
            if (nv < bnv[r]) { bnv[r] = nv; bnj[r] = jcol[s]; }
        }
    }

    // reduce across the 16 lanes of each row group (masks < 16 keep kg fixed)
    #pragma unroll
    for (int r = 0; r < 4; ++r) {
        #pragma unroll
        for (int m = 8; m > 0; m >>= 1) {
            const float opv = __shfl_xor(bpv[r], m); const int opj = __shfl_xor(bpj[r], m);
            if (opv > bpv[r] || (opv == bpv[r] && opj < bpj[r])) { bpv[r] = opv; bpj[r] = opj; }
            const float onv = __shfl_xor(bnv[r], m); const int onj = __shfl_xor(bnj[r], m);
            if (onv < bnv[r] || (onv == bnv[r] && onj < bnj[r])) { bnv[r] = onv; bnj[r] = onj; }
        }
    }

    // ---- cross-wave combine: 16 C-rows (8 real) x 8 col-chunks ----
    __shared__ float L_pv[16][8]; __shared__ int L_pj[16][8];
    __shared__ float L_nv[16][8]; __shared__ int L_nj[16][8];
    if (l15 == 0) {
        #pragma unroll
        for (int r = 0; r < 4; ++r) {
            const int rib = kg * 4 + r;
            L_pv[rib][w] = bpv[r]; L_pj[rib][w] = bpj[r];
            L_nv[rib][w] = bnv[r]; L_nj[rib][w] = bnj[r];
        }
    }
    __syncthreads();

    __shared__ int s_pp[8], s_pn[8];
    __shared__ float s_fp[8], s_cn[8];
    if (t < 8) {            // only the 8 real rows
        float pv = -1.0f; int pj = 0x7fffffff; float nv = FLT_MAX; int nj = 0x7fffffff;
        #pragma unroll
        for (int c = 0; c < 8; ++c) {   // ascending col ranges -> tie keeps first
            const float v1 = L_pv[t][c]; const int j1 = L_pj[t][c];
            if (v1 > pv || (v1 == pv && j1 < pj)) { pv = v1; pj = j1; }
            const float v2 = L_nv[t][c]; const int j2 = L_nj[t][c];
            if (v2 < nv || (v2 == nv && j2 < nj)) { nv = v2; nj = j2; }
        }
        s_pp[t] = pj > (BATCH - 1) ? (BATCH - 1) : pj;
        s_pn[t] = nj > (BATCH - 1) ? (BATCH - 1) : nj;
        s_fp[t] = (pv > 0.0f) ? sqrtf(pv + EPSV) : 0.0f;   // no-positive row -> 0
        s_cn[t] = sqrtf(nv + EPSV);
    }
    __syncthreads();

    // ---- intra distances (exact fp32): 8 rows x 16 lanes ----
    __shared__ float ls[8];
    if (t < 128) {
        const int g = t >> 4, sl = t & 15;
        const float* fB = feat + (size_t)(half ^ 1) * BATCH * DIM;  // b-side = f_intra
        const float4* x = reinterpret_cast<const float4*>(fB + (size_t)s_pp[g] * DIM + sl * 8);
        const float4* y = reinterpret_cast<const float4*>(fB + (size_t)s_pn[g] * DIM + sl * 8);
        const float4 x0 = x[0], x1 = x[1], y0 = y[0], y1 = y[1];
        float d, d2;
        d = x0.x - y0.x; d2  = d * d;  d = x0.y - y0.y; d2 += d * d;
        d = x0.z - y0.z; d2 += d * d;  d = x0.w - y0.w; d2 += d * d;
        d = x1.x - y1.x; d2 += d * d;  d = x1.y - y1.y; d2 += d * d;
        d = x1.z - y1.z; d2 += d * d;  d = x1.w - y1.w; d2 += d * d;
        d2 += __shfl_xor(d2, 1); d2 += __shfl_xor(d2, 2);
        d2 += __shfl_xor(d2, 4); d2 += __shfl_xor(d2, 8);
        if (sl == 0) {
            const float gd = sqrtf(d2 + EPSV);
            const float loss = fmaxf(s_fp[g] - s_cn[g] + MARGIN, 0.0f)
                             + LAMDA * fmaxf(INTRA_MARGIN - gd, 0.0f);
            ls[g] = loss * (1.0f / (float)BATCH);
        }
    }
    __syncthreads();

    // ---- per-block partial + last-block deterministic final sum (t==0 only) ----
    if (t == 0) {
        float s = 0.0f;
        #pragma unroll
        for (int i = 0; i < 8; ++i) s += ls[i];
        partial[rg] = s;
        __threadfence();
        const unsigned int old = atomicAdd(counter, 1u);
        if (old == (NRG - 1)) {
            __threadfence();
            float tot = 0.0f;
            for (int i = 0; i < NRG; ++i) tot += partial[i];   // fixed order -> deterministic
            out[0] = tot;
        }
    }
}

extern "C" void kernel_launch(void* const* d_in, const int* in_sizes, int n_in,
                              void* d_out, int out_size, void* d_ws, size_t ws_size,
                              hipStream_t stream) {
    const float* feat   = (const float*)d_in[0];
    const int*   label1 = (const int*)d_in[1];
    const int*   label2 = (const int*)d_in[2];
    float* out = (float*)d_out;

    char* ws = (char*)d_ws;
    float*        partial = (float*)(ws);                  // 1 KB
    unsigned int* counter = (unsigned int*)(ws + 2048);    // 4 B
    ushort*       bhi     = (ushort*)(ws + 4096);          // 512 KB
    float*        norm2   = (float*)(ws + 4096 + 512 * 1024); // 8 KB

    prep_kernel<<<dim3(256), dim3(128), 0, stream>>>(feat, bhi, norm2, counter);
    gemm_finalize_kernel<<<dim3(256), dim3(512), 0, stream>>>(
        bhi, norm2, feat, label1, label2, partial, counter, out);
}

// Round 8
// 26.881 us; speedup vs baseline: 2.8666x; 1.2178x over previous
//
#include <hip/hip_runtime.h>
#include <math.h>
#include <float.h>

#define BATCH 1024
#define DIM 128
#define EPSV 1e-12f
#define MARGIN 0.5f
#define INTRA_MARGIN 0.1f
#define LAMDA 0.5f
#define NRG 256          // row-groups of 8 rows (2048 / 8)

typedef __attribute__((ext_vector_type(8))) short s16x8;   // 8 bf16 (4 VGPRs)
typedef __attribute__((ext_vector_type(4))) float f32x4;   // MFMA C/D

__device__ __forceinline__ ushort f2bf(float f) {          // RNE fp32 -> bf16
    unsigned u = __float_as_uint(f);
    return (ushort)((u + 0x7fffu + ((u >> 16) & 1u)) >> 16);
}

// ---------------- Kernel A: feat -> bf16 + fp32 row norms ----------------
// 256 blocks x 128 threads; 16 threads per row, 8 floats per thread.
__global__ __launch_bounds__(128) void prep_kernel(
    const float* __restrict__ feat, ushort* __restrict__ bhi,
    float* __restrict__ norm2)
{
    const int t = threadIdx.x;
    const int gt  = blockIdx.x * 128 + t;  // 0..32767
    const int row = gt >> 4, seg = gt & 15;
    const float4* p = reinterpret_cast<const float4*>(feat + (size_t)row * DIM + seg * 8);
    const float4 a = p[0], b = p[1];
    const float v[8] = {a.x, a.y, a.z, a.w, b.x, b.y, b.z, b.w};
    ushort h[8];
    float n = 0.0f;
    #pragma unroll
    for (int e = 0; e < 8; ++e) {
        h[e] = f2bf(v[e]);
        n = fmaf(v[e], v[e], n);
    }
    uint4 uh;
    uh.x = (uint)h[0] | ((uint)h[1] << 16); uh.y = (uint)h[2] | ((uint)h[3] << 16);
    uh.z = (uint)h[4] | ((uint)h[5] << 16); uh.w = (uint)h[6] | ((uint)h[7] << 16);
    *reinterpret_cast<uint4*>(bhi + (size_t)row * DIM + seg * 8) = uh;
    n += __shfl_xor(n, 1); n += __shfl_xor(n, 2);
    n += __shfl_xor(n, 4); n += __shfl_xor(n, 8);
    if ((t & 15) == 0) norm2[row] = n;
}

// ---------------- Kernel B: MFMA gram + selection + intra; writes partial[rg] ----------------
// 256 blocks x 512 threads. Block = 8 rows (one half) x ALL 1024 cols.
// Wave w covers cols [w*128, w*128+128) as 8 subtiles of 16.
// MFMA A-fragment duplicates rows (l15&7); C rows 8..15 are ignored at merge.
// NO fences / NO atomics — visibility of partial[] via kernel-boundary release.
__global__ __launch_bounds__(512) void gemm_kernel(
    const ushort* __restrict__ bhi, const float* __restrict__ norm2,
    const float* __restrict__ feat,
    const int* __restrict__ label1, const int* __restrict__ label2,
    float* __restrict__ partial)
{
    const int rg    = blockIdx.x;            // 0..255
    const int half  = rg >> 7;               // 128 rowgroups per half
    const int arow0 = (rg & 127) * 8;        // row base within half
    const int aglob0 = half * BATCH + arow0; // row base in 2048-row arrays
    const int bglob0 = (half ^ 1) * BATCH;

    const int t = threadIdx.x;
    const int w = t >> 6, lane = t & 63;
    const int l15 = lane & 15, kg = lane >> 4;

    const int* labA = half ? label2 : label1;
    const int* labB = half ? label1 : label2;

    // ---- operands: 8 subtiles of 16 cols; A rows duplicated via l15&7 ----
    const size_t abase = (size_t)(aglob0 + (l15 & 7)) * DIM;
    int jcol[8]; float nb[8]; int lb[8]; size_t bbase[8];
    #pragma unroll
    for (int s = 0; s < 8; ++s) {
        jcol[s]  = w * 128 + s * 16 + l15;
        const int bg = bglob0 + jcol[s];
        bbase[s] = (size_t)bg * DIM;
        nb[s] = norm2[bg];
        lb[s] = labB[jcol[s]];
    }

    f32x4 acc[8];
    #pragma unroll
    for (int s = 0; s < 8; ++s) acc[s] = (f32x4){0.f, 0.f, 0.f, 0.f};

    #pragma unroll
    for (int kt = 0; kt < 4; ++kt) {
        const int koff = kt * 32 + kg * 8;
        const s16x8 ah = *reinterpret_cast<const s16x8*>(bhi + abase + koff);
        #pragma unroll
        for (int s = 0; s < 8; ++s) {
            const s16x8 bh = *reinterpret_cast<const s16x8*>(bhi + bbase[s] + koff);
            acc[s] = __builtin_amdgcn_mfma_f32_16x16x32_bf16(ah, bh, acc[s], 0, 0, 0);
        }
    }

    // ---- selection in d^2 domain; C/D layout: col=l15, row=kg*4+reg ----
    float na[4]; int la[4];
    #pragma unroll
    for (int r = 0; r < 4; ++r) {
        const int rr = (kg * 4 + r) & 7;
        na[r] = norm2[aglob0 + rr];
        la[r] = labA[arow0 + rr];
    }

    float bpv[4], bnv[4]; int bpj[4], bnj[4];
    #pragma unroll
    for (int r = 0; r < 4; ++r) { bpv[r] = -1.0f; bpj[r] = 0x7fffffff; bnv[r] = FLT_MAX; bnj[r] = 0x7fffffff; }

    #pragma unroll
    for (int s = 0; s < 8; ++s) {
        #pragma unroll
        for (int r = 0; r < 4; ++r) {
            const float d2 = fmaxf(na[r] + nb[s] - 2.0f * acc[s][r], 0.0f);
            const bool same = (la[r] == lb[s]);
            const float pv = same ? d2 : 0.0f;
            const float nv = same ? FLT_MAX : d2;
            // jcol ascending in s -> strict compares keep first occurrence
            if (pv > bpv[r]) { bpv[r] = pv; bpj[r] = jcol[s]; }
            if (nv < bnv[r]) { bnv[r] = nv; bnj[r] = jcol[s]; }
        }
    }

    // reduce across the 16 lanes of each row group (masks < 16 keep kg fixed)
    #pragma unroll
    for (int r = 0; r < 4; ++r) {
        #pragma unroll
        for (int m = 8; m > 0; m >>= 1) {
            const float opv = __shfl_xor(bpv[r], m); const int opj = __shfl_xor(bpj[r], m);
            if (opv > bpv[r] || (opv == bpv[r] && opj < bpj[r])) { bpv[r] = opv; bpj[r] = opj; }
            const float onv = __shfl_xor(bnv[r], m); const int onj = __shfl_xor(bnj[r], m);
            if (onv < bnv[r] || (onv == bnv[r] && onj < bnj[r])) { bnv[r] = onv; bnj[r] = onj; }
        }
    }

    // ---- cross-wave combine: 16 C-rows (8 real) x 8 col-chunks ----
    __shared__ float L_pv[16][8]; __shared__ int L_pj[16][8];
    __shared__ float L_nv[16][8]; __shared__ int L_nj[16][8];
    if (l15 == 0) {
        #pragma unroll
        for (int r = 0; r < 4; ++r) {
            const int rib = kg * 4 + r;
            L_pv[rib][w] = bpv[r]; L_pj[rib][w] = bpj[r];
            L_nv[rib][w] = bnv[r]; L_nj[rib][w] = bnj[r];
        }
    }
    __syncthreads();

    __shared__ int s_pp[8], s_pn[8];
    __shared__ float s_fp[8], s_cn[8];
    if (t < 8) {            // only the 8 real rows
        float pv = -1.0f; int pj = 0x7fffffff; float nv = FLT_MAX; int nj = 0x7fffffff;
        #pragma unroll
        for (int c = 0; c < 8; ++c) {   // ascending col ranges -> tie keeps first
            const float v1 = L_pv[t][c]; const int j1 = L_pj[t][c];
            if (v1 > pv || (v1 == pv && j1 < pj)) { pv = v1; pj = j1; }
            const float v2 = L_nv[t][c]; const int j2 = L_nj[t][c];
            if (v2 < nv || (v2 == nv && j2 < nj)) { nv = v2; nj = j2; }
        }
        s_pp[t] = pj > (BATCH - 1) ? (BATCH - 1) : pj;
        s_pn[t] = nj > (BATCH - 1) ? (BATCH - 1) : nj;
        s_fp[t] = (pv > 0.0f) ? sqrtf(pv + EPSV) : 0.0f;   // no-positive row -> 0
        s_cn[t] = sqrtf(nv + EPSV);
    }
    __syncthreads();

    // ---- intra distances (exact fp32): 8 rows x 16 lanes ----
    __shared__ float ls[8];
    if (t < 128) {
        const int g = t >> 4, sl = t & 15;
        const float* fB = feat + (size_t)(half ^ 1) * BATCH * DIM;  // b-side = f_intra
        const float4* x = reinterpret_cast<const float4*>(fB + (size_t)s_pp[g] * DIM + sl * 8);
        const float4* y = reinterpret_cast<const float4*>(fB + (size_t)s_pn[g] * DIM + sl * 8);
        const float4 x0 = x[0], x1 = x[1], y0 = y[0], y1 = y[1];
        float d, d2;
        d = x0.x - y0.x; d2  = d * d;  d = x0.y - y0.y; d2 += d * d;
        d = x0.z - y0.z; d2 += d * d;  d = x0.w - y0.w; d2 += d * d;
        d = x1.x - y1.x; d2 += d * d;  d = x1.y - y1.y; d2 += d * d;
        d = x1.z - y1.z; d2 += d * d;  d = x1.w - y1.w; d2 += d * d;
        d2 += __shfl_xor(d2, 1); d2 += __shfl_xor(d2, 2);
        d2 += __shfl_xor(d2, 4); d2 += __shfl_xor(d2, 8);
        if (sl == 0) {
            const float gd = sqrtf(d2 + EPSV);
            const float loss = fmaxf(s_fp[g] - s_cn[g] + MARGIN, 0.0f)
                             + LAMDA * fmaxf(INTRA_MARGIN - gd, 0.0f);
            ls[g] = loss * (1.0f / (float)BATCH);
        }
    }
    __syncthreads();

    if (t == 0) {
        float s = 0.0f;
        #pragma unroll
        for (int i = 0; i < 8; ++i) s += ls[i];
        partial[rg] = s;
    }
}

// ---------------- Kernel C: deterministic reduce of 256 partials ----------------
__global__ __launch_bounds__(256) void reduce_kernel(
    const float* __restrict__ partial, float* __restrict__ out)
{
    const int t = threadIdx.x;
    float s = partial[t];
    #pragma unroll
    for (int m = 32; m > 0; m >>= 1) s += __shfl_down(s, m);
    __shared__ float ws4[4];
    if ((t & 63) == 0) ws4[t >> 6] = s;
    __syncthreads();
    if (t == 0) out[0] = ws4[0] + ws4[1] + ws4[2] + ws4[3];
}

extern "C" void kernel_launch(void* const* d_in, const int* in_sizes, int n_in,
                              void* d_out, int out_size, void* d_ws, size_t ws_size,
                              hipStream_t stream) {
    const float* feat   = (const float*)d_in[0];
    const int*   label1 = (const int*)d_in[1];
    const int*   label2 = (const int*)d_in[2];
    float* out = (float*)d_out;

    char* ws = (char*)d_ws;
    float*  partial = (float*)(ws);                        // 1 KB
    ushort* bhi     = (ushort*)(ws + 4096);                // 512 KB
    float*  norm2   = (float*)(ws + 4096 + 512 * 1024);    // 8 KB

    prep_kernel<<<dim3(256), dim3(128), 0, stream>>>(feat, bhi, norm2);
    gemm_kernel<<<dim3(256), dim3(512), 0, stream>>>(
        bhi, norm2, feat, label1, label2, partial);
    reduce_kernel<<<dim3(1), dim3(256), 0, stream>>>(partial, out);
}

// Round 9
// 26.577 us; speedup vs baseline: 2.8994x; 1.0114x over previous
//
#include <hip/hip_runtime.h>
#include <math.h>
#include <float.h>

#define BATCH 1024
#define DIM 128
#define EPSV 1e-12f
#define MARGIN 0.5f
#define INTRA_MARGIN 0.1f
#define LAMDA 0.5f

typedef __attribute__((ext_vector_type(8))) short s16x8;   // 8 bf16 (4 VGPRs)
typedef __attribute__((ext_vector_type(4))) float f32x4;   // MFMA C/D

__device__ __forceinline__ ushort f2bf(float f) {          // RNE fp32 -> bf16
    unsigned u = __float_as_uint(f);
    return (ushort)((u + 0x7fffu + ((u >> 16) & 1u)) >> 16);
}

// ---------------- Kernel A: feat -> bf16 + fp32 row norms ----------------
// 256 blocks x 128 threads; 16 threads per row, 8 floats per thread.
__global__ __launch_bounds__(128) void prep_kernel(
    const float* __restrict__ feat, ushort* __restrict__ bhi,
    float* __restrict__ norm2)
{
    const int t = threadIdx.x;
    const int gt  = blockIdx.x * 128 + t;  // 0..32767
    const int row = gt >> 4, seg = gt & 15;
    const float4* p = reinterpret_cast<const float4*>(feat + (size_t)row * DIM + seg * 8);
    const float4 a = p[0], b = p[1];
    const float v[8] = {a.x, a.y, a.z, a.w, b.x, b.y, b.z, b.w};
    ushort h[8];
    float n = 0.0f;
    #pragma unroll
    for (int e = 0; e < 8; ++e) {
        h[e] = f2bf(v[e]);
        n = fmaf(v[e], v[e], n);
    }
    uint4 uh;
    uh.x = (uint)h[0] | ((uint)h[1] << 16); uh.y = (uint)h[2] | ((uint)h[3] << 16);
    uh.z = (uint)h[4] | ((uint)h[5] << 16); uh.w = (uint)h[6] | ((uint)h[7] << 16);
    *reinterpret_cast<uint4*>(bhi + (size_t)row * DIM + seg * 8) = uh;
    n += __shfl_xor(n, 1); n += __shfl_xor(n, 2);
    n += __shfl_xor(n, 4); n += __shfl_xor(n, 8);
    if ((t & 15) == 0) norm2[row] = n;
}

// ---------------- Kernel B: MFMA gram + selection + intra; writes partial[rg] ----------------
// 256 blocks x 512 threads. Block = 8 rows (one half) x ALL 1024 cols.
// Wave w covers cols [w*128, w*128+128) as 8 subtiles of 16.
// FULL-DEPTH PREFETCH: all 36 fragment loads issued before any MFMA
// (launch_bounds(512,2) raises the VGPR cap to 256 so they stay in flight).
__global__ __launch_bounds__(512, 2) void gemm_kernel(
    const ushort* __restrict__ bhi, const float* __restrict__ norm2,
    const float* __restrict__ feat,
    const int* __restrict__ label1, const int* __restrict__ label2,
    float* __restrict__ partial)
{
    const int rg    = blockIdx.x;            // 0..255
    const int half  = rg >> 7;               // 128 rowgroups per half
    const int arow0 = (rg & 127) * 8;        // row base within half
    const int aglob0 = half * BATCH + arow0; // row base in 2048-row arrays
    const int bglob0 = (half ^ 1) * BATCH;

    const int t = threadIdx.x;
    const int w = t >> 6, lane = t & 63;
    const int l15 = lane & 15, kg = lane >> 4;

    const int* labA = half ? label2 : label1;
    const int* labB = half ? label1 : label2;

    // ---- addresses ----
    const size_t abase = (size_t)(aglob0 + (l15 & 7)) * DIM;
    int jcol[8]; size_t bbase[8];
    #pragma unroll
    for (int s = 0; s < 8; ++s) {
        jcol[s]  = w * 128 + s * 16 + l15;
        bbase[s] = (size_t)(bglob0 + jcol[s]) * DIM;
    }

    // ---- issue ALL fragment loads up front (36 global_load_dwordx4 in flight) ----
    s16x8 ah[4], bh[4][8];
    #pragma unroll
    for (int kt = 0; kt < 4; ++kt) {
        const int koff = kt * 32 + kg * 8;
        ah[kt] = *reinterpret_cast<const s16x8*>(bhi + abase + koff);
        #pragma unroll
        for (int s = 0; s < 8; ++s)
            bh[kt][s] = *reinterpret_cast<const s16x8*>(bhi + bbase[s] + koff);
    }

    // ---- scalar-side loads issued early too (complete under the MFMAs) ----
    float nb[8]; int lb[8];
    #pragma unroll
    for (int s = 0; s < 8; ++s) {
        nb[s] = norm2[bglob0 + jcol[s]];
        lb[s] = labB[jcol[s]];
    }
    float na[4]; int la[4];
    #pragma unroll
    for (int r = 0; r < 4; ++r) {
        const int rr = (kg * 4 + r) & 7;
        na[r] = norm2[aglob0 + rr];
        la[r] = labA[arow0 + rr];
    }

    // ---- MFMA accumulation ----
    f32x4 acc[8];
    #pragma unroll
    for (int s = 0; s < 8; ++s) acc[s] = (f32x4){0.f, 0.f, 0.f, 0.f};
    #pragma unroll
    for (int kt = 0; kt < 4; ++kt) {
        #pragma unroll
        for (int s = 0; s < 8; ++s)
            acc[s] = __builtin_amdgcn_mfma_f32_16x16x32_bf16(ah[kt], bh[kt][s], acc[s], 0, 0, 0);
    }

    // ---- selection in d^2 domain; C/D layout: col=l15, row=kg*4+reg ----
    float bpv[4], bnv[4]; int bpj[4], bnj[4];
    #pragma unroll
    for (int r = 0; r < 4; ++r) { bpv[r] = -1.0f; bpj[r] = 0x7fffffff; bnv[r] = FLT_MAX; bnj[r] = 0x7fffffff; }

    #pragma unroll
    for (int s = 0; s < 8; ++s) {
        #pragma unroll
        for (int r = 0; r < 4; ++r) {
            const float d2 = fmaxf(na[r] + nb[s] - 2.0f * acc[s][r], 0.0f);
            const bool same = (la[r] == lb[s]);
            const float pv = same ? d2 : 0.0f;
            const float nv = same ? FLT_MAX : d2;
            // jcol ascending in s -> strict compares keep first occurrence
            if (pv > bpv[r]) { bpv[r] = pv; bpj[r] = jcol[s]; }
            if (nv < bnv[r]) { bnv[r] = nv; bnj[r] = jcol[s]; }
        }
    }

    // reduce across the 16 lanes of each row group (masks < 16 keep kg fixed)
    #pragma unroll
    for (int r = 0; r < 4; ++r) {
        #pragma unroll
        for (int m = 8; m > 0; m >>= 1) {
            const float opv = __shfl_xor(bpv[r], m); const int opj = __shfl_xor(bpj[r], m);
            if (opv > bpv[r] || (opv == bpv[r] && opj < bpj[r])) { bpv[r] = opv; bpj[r] = opj; }
            const float onv = __shfl_xor(bnv[r], m); const int onj = __shfl_xor(bnj[r], m);
            if (onv < bnv[r] || (onv == bnv[r] && onj < bnj[r])) { bnv[r] = onv; bnj[r] = onj; }
        }
    }

    // ---- cross-wave combine: 16 C-rows (8 real) x 8 col-chunks ----
    __shared__ float L_pv[16][8]; __shared__ int L_pj[16][8];
    __shared__ float L_nv[16][8]; __shared__ int L_nj[16][8];
    if (l15 == 0) {
        #pragma unroll
        for (int r = 0; r < 4; ++r) {
            const int rib = kg * 4 + r;
            L_pv[rib][w] = bpv[r]; L_pj[rib][w] = bpj[r];
            L_nv[rib][w] = bnv[r]; L_nj[rib][w] = bnj[r];
        }
    }
    __syncthreads();

    __shared__ int s_pp[8], s_pn[8];
    __shared__ float s_fp[8], s_cn[8];
    if (t < 8) {            // only the 8 real rows
        float pv = -1.0f; int pj = 0x7fffffff; float nv = FLT_MAX; int nj = 0x7fffffff;
        #pragma unroll
        for (int c = 0; c < 8; ++c) {   // ascending col ranges -> tie keeps first
            const float v1 = L_pv[t][c]; const int j1 = L_pj[t][c];
            if (v1 > pv || (v1 == pv && j1 < pj)) { pv = v1; pj = j1; }
            const float v2 = L_nv[t][c]; const int j2 = L_nj[t][c];
            if (v2 < nv || (v2 == nv && j2 < nj)) { nv = v2; nj = j2; }
        }
        s_pp[t] = pj > (BATCH - 1) ? (BATCH - 1) : pj;
        s_pn[t] = nj > (BATCH - 1) ? (BATCH - 1) : nj;
        s_fp[t] = (pv > 0.0f) ? sqrtf(pv + EPSV) : 0.0f;   // no-positive row -> 0
        s_cn[t] = sqrtf(nv + EPSV);
    }
    __syncthreads();

    // ---- intra distances (exact fp32): 8 rows x 16 lanes ----
    __shared__ float ls[8];
    if (t < 128) {
        const int g = t >> 4, sl = t & 15;
        const float* fB = feat + (size_t)(half ^ 1) * BATCH * DIM;  // b-side = f_intra
        const float4* x = reinterpret_cast<const float4*>(fB + (size_t)s_pp[g] * DIM + sl * 8);
        const float4* y = reinterpret_cast<const float4*>(fB + (size_t)s_pn[g] * DIM + sl * 8);
        const float4 x0 = x[0], x1 = x[1], y0 = y[0], y1 = y[1];
        float d, d2;
        d = x0.x - y0.x; d2  = d * d;  d = x0.y - y0.y; d2 += d * d;
        d = x0.z - y0.z; d2 += d * d;  d = x0.w - y0.w; d2 += d * d;
        d = x1.x - y1.x; d2 += d * d;  d = x1.y - y1.y; d2 += d * d;
        d = x1.z - y1.z; d2 += d * d;  d = x1.w - y1.w; d2 += d * d;
        d2 += __shfl_xor(d2, 1); d2 += __shfl_xor(d2, 2);
        d2 += __shfl_xor(d2, 4); d2 += __shfl_xor(d2, 8);
        if (sl == 0) {
            const float gd = sqrtf(d2 + EPSV);
            const float loss = fmaxf(s_fp[g] - s_cn[g] + MARGIN, 0.0f)
                             + LAMDA * fmaxf(INTRA_MARGIN - gd, 0.0f);
            ls[g] = loss * (1.0f / (float)BATCH);
        }
    }
    __syncthreads();

    if (t == 0) {
        float s = 0.0f;
        #pragma unroll
        for (int i = 0; i < 8; ++i) s += ls[i];
        partial[rg] = s;
    }
}

// ---------------- Kernel C: deterministic reduce of 256 partials ----------------
__global__ __launch_bounds__(256) void reduce_kernel(
    const float* __restrict__ partial, float* __restrict__ out)
{
    const int t = threadIdx.x;
    float s = partial[t];
    #pragma unroll
    for (int m = 32; m > 0; m >>= 1) s += __shfl_down(s, m);
    __shared__ float ws4[4];
    if ((t & 63) == 0) ws4[t >> 6] = s;
    __syncthreads();
    if (t == 0) out[0] = ws4[0] + ws4[1] + ws4[2] + ws4[3];
}

extern "C" void kernel_launch(void* const* d_in, const int* in_sizes, int n_in,
                              void* d_out, int out_size, void* d_ws, size_t ws_size,
                              hipStream_t stream) {
    const float* feat   = (const float*)d_in[0];
    const int*   label1 = (const int*)d_in[1];
    const int*   label2 = (const int*)d_in[2];
    float* out = (float*)d_out;

    char* ws = (char*)d_ws;
    float*  partial = (float*)(ws);                        // 1 KB
    ushort* bhi     = (ushort*)(ws + 4096);                // 512 KB
    float*  norm2   = (float*)(ws + 4096 + 512 * 1024);    // 8 KB

    prep_kernel<<<dim3(256), dim3(128), 0, stream>>>(feat, bhi, norm2);
    gemm_kernel<<<dim3(256), dim3(512), 0, stream>>>(
        bhi, norm2, feat, label1, label2, partial);
    reduce_kernel<<<dim3(1), dim3(256), 0, stream>>>(partial, out);
}